// Round 1
// baseline (313.536 us; speedup 1.0000x reference)
//
#include <hip/hip_runtime.h>
#include <hip/hip_bf16.h>

// Problem constants (fixed by reference: features_1 [1,20000,256] f32,
// features_2 [1,8192,256] f32, map21 [8192] int)
#define PP      8192
#define DIM     256
#define NCHUNK  8            // column chunks (grid.y of main kernel)
#define CTILES  (PP / 16 / NCHUNK)   // 64 column tiles of 16 per chunk

typedef __bf16 bf16_t;
using bf16x8 = __attribute__((ext_vector_type(8))) __bf16;
using bf16x4 = __attribute__((ext_vector_type(4))) __bf16;
using f32x4  = __attribute__((ext_vector_type(4))) float;

// log2(e)/T : converts -dist to log2-domain logits
#define C2 20.609929155556618f
// ln(2)
#define LN2 0.6931471805599453f

// ---------------------------------------------------------------------------
// Kernel 1: gather + bf16 convert + fp32 norms + exact diagonal logit.
// One wave per row p: q = f1[map21[p]], k = f2[p]. Lane handles 4 floats.
// ---------------------------------------------------------------------------
__global__ __launch_bounds__(256) void nce_prep(
    const float* __restrict__ f1, const float* __restrict__ f2,
    const int* __restrict__ map,
    bf16_t* __restrict__ qb, bf16_t* __restrict__ kb,
    float* __restrict__ qsq, float* __restrict__ ksq,
    float* __restrict__ diag2)
{
    const int wave = threadIdx.x >> 6;
    const int lane = threadIdx.x & 63;
    const int p = blockIdx.x * 4 + wave;

    const int idx = map[p];
    const f32x4 qv = *(const f32x4*)(f1 + (long long)idx * DIM + lane * 4);
    const f32x4 kv = *(const f32x4*)(f2 + (long long)p * DIM + lane * 4);

    float qs = qv[0]*qv[0] + qv[1]*qv[1] + qv[2]*qv[2] + qv[3]*qv[3];
    float ks = kv[0]*kv[0] + kv[1]*kv[1] + kv[2]*kv[2] + kv[3]*kv[3];
    const f32x4 dv = qv - kv;
    float ds = dv[0]*dv[0] + dv[1]*dv[1] + dv[2]*dv[2] + dv[3]*dv[3];

    bf16x4 qo, ko;
    #pragma unroll
    for (int i = 0; i < 4; ++i) { qo[i] = (bf16_t)qv[i]; ko[i] = (bf16_t)kv[i]; }
    *(bf16x4*)(qb + p * DIM + lane * 4) = qo;
    *(bf16x4*)(kb + p * DIM + lane * 4) = ko;

    #pragma unroll
    for (int s = 32; s > 0; s >>= 1) {
        qs += __shfl_xor(qs, s);
        ks += __shfl_xor(ks, s);
        ds += __shfl_xor(ds, s);
    }
    if (lane == 0) {
        qsq[p]   = qs;
        ksq[p]   = ks;
        diag2[p] = -__builtin_amdgcn_sqrtf(ds) * C2;   // diagonal logit, log2 domain
    }
}

// ---------------------------------------------------------------------------
// Kernel 2: fused QK^T + dist + online (per-lane lazy) logsumexp partials.
// Block = 4 waves, 64 rows; wave = 16 rows; sweeps one 1024-col chunk.
// A fragments (K=256) live in registers; B fragments stream from L2/L3.
// No LDS, no __syncthreads.
// ---------------------------------------------------------------------------
__global__ __launch_bounds__(256) void nce_main(
    const bf16_t* __restrict__ qb, const bf16_t* __restrict__ kb,
    const float* __restrict__ qsq, const float* __restrict__ ksq,
    float* __restrict__ part_m, float* __restrict__ part_l)
{
    const int wave = threadIdx.x >> 6;
    const int lane = threadIdx.x & 63;
    const int quad = lane >> 4;
    const int l15  = lane & 15;
    const int r0 = blockIdx.x * 64 + wave * 16;     // wave's first row
    const int c0 = blockIdx.y * (CTILES * 16);      // chunk's first column

    // A fragments: A[m=lane&15][k=quad*8+j], 8 frags cover K=256 (32 VGPRs)
    bf16x8 a[8];
    {
        const bf16_t* aptr = qb + (r0 + l15) * DIM + quad * 8;
        #pragma unroll
        for (int kk = 0; kk < 8; ++kk)
            a[kk] = *(const bf16x8*)(aptr + kk * 32);
    }

    // qsq for this lane's 4 accumulator rows (row = quad*4 + r)
    float qs[4];
    #pragma unroll
    for (int r = 0; r < 4; ++r) qs[r] = qsq[r0 + quad * 4 + r];

    // per-lane online state (log2 domain), 4 rows each
    float m[4], l[4];
    #pragma unroll
    for (int r = 0; r < 4; ++r) { m[r] = -1.0e30f; l[r] = 0.0f; }

    const bf16_t* bptr = kb + (c0 + l15) * DIM + quad * 8;
    const float*  kqp  = ksq + c0 + l15;

    for (int t = 0; t < CTILES; ++t) {
        bf16x8 b[8];
        #pragma unroll
        for (int kk = 0; kk < 8; ++kk)
            b[kk] = *(const bf16x8*)(bptr + kk * 32);
        bptr += 16 * DIM;
        const float kq = *kqp;
        kqp += 16;

        f32x4 acc0 = {0.0f, 0.0f, 0.0f, 0.0f};
        f32x4 acc1 = {0.0f, 0.0f, 0.0f, 0.0f};
        #pragma unroll
        for (int kk = 0; kk < 4; ++kk) {
            acc0 = __builtin_amdgcn_mfma_f32_16x16x32_bf16(a[2*kk],   b[2*kk],   acc0, 0, 0, 0);
            acc1 = __builtin_amdgcn_mfma_f32_16x16x32_bf16(a[2*kk+1], b[2*kk+1], acc1, 0, 0, 0);
        }

        #pragma unroll
        for (int r = 0; r < 4; ++r) {
            float sq = qs[r] + kq - 2.0f * (acc0[r] + acc1[r]);
            sq = fmaxf(sq, 0.0f);
            const float lg = -__builtin_amdgcn_sqrtf(sq) * C2;  // logit, log2 domain
            const float mo = m[r];
            const float mn = fmaxf(mo, lg);
            // l = l * 2^(mo-mn) + 2^(lg-mn)   (scale == 1 when max unchanged)
            l[r] = l[r] * __builtin_amdgcn_exp2f(mo - mn)
                 + __builtin_amdgcn_exp2f(lg - mn);
            m[r] = mn;
        }
    }

    // merge (m,l) across the 16 column-lanes (butterfly within 16-lane group)
    #pragma unroll
    for (int s = 1; s < 16; s <<= 1) {
        #pragma unroll
        for (int r = 0; r < 4; ++r) {
            const float mo = __shfl_xor(m[r], s);
            const float lo = __shfl_xor(l[r], s);
            const float mn = fmaxf(m[r], mo);
            l[r] = l[r] * __builtin_amdgcn_exp2f(m[r] - mn)
                 + lo   * __builtin_amdgcn_exp2f(mo   - mn);
            m[r] = mn;
        }
    }

    if (l15 == 0) {
        const int base = blockIdx.y * PP;
        #pragma unroll
        for (int r = 0; r < 4; ++r) {
            const int row = r0 + quad * 4 + r;
            part_m[base + row] = m[r];
            part_l[base + row] = l[r];
        }
    }
}

// ---------------------------------------------------------------------------
// Kernel 3: merge chunk partials per row, subtract diagonal, reduce to loss.
// Single block (no atomics, no memset needed).
// ---------------------------------------------------------------------------
__global__ __launch_bounds__(1024) void nce_final(
    const float* __restrict__ part_m, const float* __restrict__ part_l,
    const float* __restrict__ diag2, float* __restrict__ out)
{
    __shared__ float red[1024];
    float sum = 0.0f;
    for (int row = threadIdx.x; row < PP; row += 1024) {
        float m = part_m[row];
        float l = part_l[row];
        #pragma unroll
        for (int c = 1; c < NCHUNK; ++c) {
            const float mc = part_m[c * PP + row];
            const float lc = part_l[c * PP + row];
            const float mn = fmaxf(m, mc);
            l = l * __builtin_amdgcn_exp2f(m - mn) + lc * __builtin_amdgcn_exp2f(mc - mn);
            m = mn;
        }
        // row_loss (log2 domain) = logsumexp2 - diag2
        sum += m + __builtin_amdgcn_logf(l) - diag2[row];
    }
    red[threadIdx.x] = sum;
    __syncthreads();
    for (int s = 512; s > 0; s >>= 1) {
        if (threadIdx.x < s) red[threadIdx.x] += red[threadIdx.x + s];
        __syncthreads();
    }
    if (threadIdx.x == 0) out[0] = red[0] * (LN2 / (float)PP);
}

// ---------------------------------------------------------------------------
extern "C" void kernel_launch(void* const* d_in, const int* in_sizes, int n_in,
                              void* d_out, int out_size, void* d_ws, size_t ws_size,
                              hipStream_t stream)
{
    const float* f1  = (const float*)d_in[0];   // [20000,256] f32
    const float* f2  = (const float*)d_in[1];   // [8192,256] f32
    const int*   map = (const int*)d_in[2];     // [8192] int
    float* out = (float*)d_out;

    // workspace layout
    char* ws = (char*)d_ws;
    bf16_t* qb    = (bf16_t*)ws;                                  // 4 MB
    bf16_t* kb    = qb + (size_t)PP * DIM;                        // 4 MB
    float*  qsq   = (float*)(ws + 2ull * PP * DIM * sizeof(bf16_t)); // 32 KB
    float*  ksq   = qsq + PP;                                     // 32 KB
    float*  diag2 = ksq + PP;                                     // 32 KB
    float*  part_m = diag2 + PP;                                  // NCHUNK*32 KB
    float*  part_l = part_m + (size_t)NCHUNK * PP;                // NCHUNK*32 KB

    nce_prep<<<PP / 4, 256, 0, stream>>>(f1, f2, map, qb, kb, qsq, ksq, diag2);
    nce_main<<<dim3(PP / 64, NCHUNK), 256, 0, stream>>>(qb, kb, qsq, ksq, part_m, part_l);
    nce_final<<<1, 1024, 0, stream>>>(part_m, part_l, diag2, out);
}

// Round 2
// 135.552 us; speedup vs baseline: 2.3130x; 2.3130x over previous
//
#include <hip/hip_runtime.h>
#include <hip/hip_bf16.h>

// Problem constants: features_1 [1,20000,256] f32, features_2 [1,8192,256] f32,
// map21 [8192] int
#define PP      8192
#define DIM     256
#define NCHUNK  16           // column chunks (grid.y of main); chunk = 512 cols
#define TCOLS   16           // 32-col tiles per chunk

typedef __bf16 bf16_t;
using bf16x8 = __attribute__((ext_vector_type(8))) __bf16;
using bf16x4 = __attribute__((ext_vector_type(4))) __bf16;
using f32x4  = __attribute__((ext_vector_type(4))) float;
using f32x16 = __attribute__((ext_vector_type(16))) float;

typedef __attribute__((address_space(1))) void as1_void;
typedef __attribute__((address_space(3))) void as3_void;

// log2(e)/T : converts -dist to log2-domain logits
#define C2 20.609929155556618f
#define LN2 0.6931471805599453f

// ---------------------------------------------------------------------------
// Fragment-major layout for a 32-row group G of a [*,256] bf16 matrix:
//   element (p, k):  G=p>>5, l31=p&31, kk=k>>4, h=(k>>3)&1, j=k&7
//   bf16 index = G*8192 + (kk*64 + h*32 + l31)*8 + j
// A wave reading frag kk at "ptr + lane*8 + kk*512" gets A[m=l31][k=kk*16+h*8+j]
// with consecutive lanes -> consecutive 16B (perfect coalescing / LDS banks).
// ---------------------------------------------------------------------------

// ---------------------------------------------------------------------------
// Kernel 1: gather + bf16 convert into frag-major layout + fp32 norms +
// exact diagonal logit. One wave per row p; lane covers k = lane*4 .. +3.
// ---------------------------------------------------------------------------
__global__ __launch_bounds__(256) void nce_prep(
    const float* __restrict__ f1, const float* __restrict__ f2,
    const int* __restrict__ map,
    bf16_t* __restrict__ qb2, bf16_t* __restrict__ kb2,
    float* __restrict__ qsq, float* __restrict__ ksq,
    float* __restrict__ diag2)
{
    const int wave = threadIdx.x >> 6;
    const int lane = threadIdx.x & 63;
    const int p = blockIdx.x * 4 + wave;

    const int idx = map[p];
    const f32x4 qv = *(const f32x4*)(f1 + (size_t)idx * DIM + lane * 4);
    const f32x4 kv = *(const f32x4*)(f2 + (size_t)p * DIM + lane * 4);

    float qs = qv[0]*qv[0] + qv[1]*qv[1] + qv[2]*qv[2] + qv[3]*qv[3];
    float ks = kv[0]*kv[0] + kv[1]*kv[1] + kv[2]*kv[2] + kv[3]*kv[3];
    const f32x4 dv = qv - kv;
    float ds = dv[0]*dv[0] + dv[1]*dv[1] + dv[2]*dv[2] + dv[3]*dv[3];

    bf16x4 qo, ko;
    #pragma unroll
    for (int i = 0; i < 4; ++i) { qo[i] = (bf16_t)qv[i]; ko[i] = (bf16_t)kv[i]; }

    const int G = p >> 5, l31 = p & 31;
    const int kk = lane >> 2, h = (lane >> 1) & 1, j0 = (lane & 1) * 4;
    const size_t off = (size_t)G * 8192 + (size_t)(kk * 64 + h * 32 + l31) * 8 + j0;
    *(bf16x4*)(qb2 + off) = qo;
    *(bf16x4*)(kb2 + off) = ko;

    #pragma unroll
    for (int s = 32; s > 0; s >>= 1) {
        qs += __shfl_xor(qs, s);
        ks += __shfl_xor(ks, s);
        ds += __shfl_xor(ds, s);
    }
    if (lane == 0) {
        qsq[p]   = qs;
        ksq[p]   = ks;
        diag2[p] = -__builtin_amdgcn_sqrtf(ds) * C2;   // diagonal logit, log2 dom
    }
}

// ---------------------------------------------------------------------------
// Stage one 32-col B tile (16 KB, already frag-major) into LDS via
// global_load_lds width-16: pure linear copy, wave-uniform base + lane*16.
// ---------------------------------------------------------------------------
__device__ __forceinline__ void stage_tile(const bf16_t* __restrict__ kb2,
                                           int Gc, int wave, int lane, char* dst)
{
    const bf16_t* src = kb2 + (size_t)Gc * 8192 + (size_t)(wave * 256 + lane) * 8;
    char* d = dst + wave * 4096;
    #pragma unroll
    for (int j = 0; j < 4; ++j) {
        __builtin_amdgcn_global_load_lds((const as1_void*)(src + j * 512),
                                         (as3_void*)(d + j * 1024), 16, 0, 0);
    }
}

// ---------------------------------------------------------------------------
// Kernel 2: fused QK^T (32x32x16 MFMA) + dist + online logsumexp partials.
// Block = 4 waves = 128 rows; wave = 32 rows x 32 cols per tile-iter.
// B tiles double-buffered in LDS (2 x 16 KB), ONE barrier per iteration:
//   barrier -> stage(t+1) [lands during compute(t)] -> compute(t)
// ---------------------------------------------------------------------------
__global__ __launch_bounds__(256) void nce_main(
    const bf16_t* __restrict__ qb2, const bf16_t* __restrict__ kb2,
    const float* __restrict__ qsq, const float* __restrict__ ksq,
    float* __restrict__ part_m, float* __restrict__ part_l)
{
    const int tid  = threadIdx.x;
    const int wave = tid >> 6;
    const int lane = tid & 63;
    const int l31  = lane & 31;
    const int h    = lane >> 5;
    const int G    = blockIdx.x * 4 + wave;   // 32-row group id
    const int r0   = G * 32;
    const int c0   = blockIdx.y * (TCOLS * 32);

    __shared__ __align__(16) char smem[2][16384];

    // A fragments: 16 x bf16x8 = 64 VGPRs, coalesced 1KB/instr loads
    bf16x8 a[16];
    {
        const bf16_t* ap = qb2 + (size_t)G * 8192 + lane * 8;
        #pragma unroll
        for (int kk = 0; kk < 16; ++kk)
            a[kk] = *(const bf16x8*)(ap + kk * 512);
    }

    // qsq for this lane's 16 accumulator rows: row = (i&3)+8*(i>>2)+4*h
    float qs[16];
    #pragma unroll
    for (int i = 0; i < 16; ++i)
        qs[i] = qsq[r0 + (i & 3) + 8 * (i >> 2) + 4 * h];

    float m[16], l[16];
    #pragma unroll
    for (int i = 0; i < 16; ++i) { m[i] = -1.0e30f; l[i] = 0.0f; }

    stage_tile(kb2, blockIdx.y * TCOLS, wave, lane, smem[0]);

    for (int t = 0; t < TCOLS; ++t) {
        __syncthreads();   // drains vmcnt: stage(t) landed; buf[(t+1)&1] free
        if (t + 1 < TCOLS)
            stage_tile(kb2, blockIdx.y * TCOLS + t + 1, wave, lane, smem[(t + 1) & 1]);

        const float kq = ksq[c0 + t * 32 + l31];

        const bf16_t* bp = (const bf16_t*)smem[t & 1] + lane * 8;
        f32x16 acc = {0.0f,0.0f,0.0f,0.0f, 0.0f,0.0f,0.0f,0.0f,
                      0.0f,0.0f,0.0f,0.0f, 0.0f,0.0f,0.0f,0.0f};
        #pragma unroll
        for (int kk = 0; kk < 16; ++kk) {
            const bf16x8 b = *(const bf16x8*)(bp + kk * 512);
            acc = __builtin_amdgcn_mfma_f32_32x32x16_bf16(a[kk], b, acc, 0, 0, 0);
        }

        #pragma unroll
        for (int i = 0; i < 16; ++i) {
            float sq = fmaf(-2.0f, acc[i], qs[i] + kq);
            sq = fmaxf(sq, 0.0f);
            const float lg = __builtin_amdgcn_sqrtf(sq) * (-C2);  // logit, log2
            const float mo = m[i];
            const float mn = fmaxf(mo, lg);
            l[i] = l[i] * __builtin_amdgcn_exp2f(mo - mn)
                 + __builtin_amdgcn_exp2f(lg - mn);
            m[i] = mn;
        }
    }

    // merge (m,l) across the 32 column-lanes (stays within same h-half)
    #pragma unroll
    for (int s = 1; s < 32; s <<= 1) {
        #pragma unroll
        for (int i = 0; i < 16; ++i) {
            const float mo = __shfl_xor(m[i], s);
            const float lo = __shfl_xor(l[i], s);
            const float mn = fmaxf(m[i], mo);
            l[i] = l[i] * __builtin_amdgcn_exp2f(m[i] - mn)
                 + lo   * __builtin_amdgcn_exp2f(mo   - mn);
            m[i] = mn;
        }
    }

    if (l31 == 0) {
        const size_t base = (size_t)blockIdx.y * PP;
        #pragma unroll
        for (int i = 0; i < 16; ++i) {
            const int row = r0 + (i & 3) + 8 * (i >> 2) + 4 * h;
            part_m[base + row] = m[i];
            part_l[base + row] = l[i];
        }
    }
}

// ---------------------------------------------------------------------------
// Kernel 3a: zero the output accumulator (harness poisons d_out each launch).
// ---------------------------------------------------------------------------
__global__ void nce_zero(float* __restrict__ out)
{
    if (threadIdx.x == 0) out[0] = 0.0f;
}

// ---------------------------------------------------------------------------
// Kernel 3b: merge chunk partials per row, subtract diagonal, reduce, atomic.
// 64 blocks x 128 threads (1 row per thread).
// ---------------------------------------------------------------------------
__global__ __launch_bounds__(128) void nce_final(
    const float* __restrict__ part_m, const float* __restrict__ part_l,
    const float* __restrict__ diag2, float* __restrict__ out)
{
    const int row = blockIdx.x * 128 + threadIdx.x;
    float m = part_m[row];
    float l = part_l[row];
    #pragma unroll
    for (int c = 1; c < NCHUNK; ++c) {
        const float mc = part_m[(size_t)c * PP + row];
        const float lc = part_l[(size_t)c * PP + row];
        const float mn = fmaxf(m, mc);
        l = l * __builtin_amdgcn_exp2f(m - mn) + lc * __builtin_amdgcn_exp2f(mc - mn);
        m = mn;
    }
    float v = m + __builtin_amdgcn_logf(l) - diag2[row];   // row loss, log2 dom

    #pragma unroll
    for (int s = 32; s > 0; s >>= 1) v += __shfl_xor(v, s);
    __shared__ float tmp[2];
    if ((threadIdx.x & 63) == 0) tmp[threadIdx.x >> 6] = v;
    __syncthreads();
    if (threadIdx.x == 0)
        atomicAdd(out, (tmp[0] + tmp[1]) * (LN2 / (float)PP));
}

// ---------------------------------------------------------------------------
extern "C" void kernel_launch(void* const* d_in, const int* in_sizes, int n_in,
                              void* d_out, int out_size, void* d_ws, size_t ws_size,
                              hipStream_t stream)
{
    const float* f1  = (const float*)d_in[0];   // [20000,256] f32
    const float* f2  = (const float*)d_in[1];   // [8192,256] f32
    const int*   map = (const int*)d_in[2];     // [8192] int
    float* out = (float*)d_out;

    // workspace layout
    char* ws = (char*)d_ws;
    bf16_t* qb2   = (bf16_t*)ws;                                      // 4 MB
    bf16_t* kb2   = qb2 + (size_t)PP * DIM;                           // 4 MB
    float*  qsq   = (float*)(ws + 2ull * PP * DIM * sizeof(bf16_t));  // 32 KB
    float*  ksq   = qsq + PP;                                         // 32 KB
    float*  diag2 = ksq + PP;                                         // 32 KB
    float*  part_m = diag2 + PP;                                      // 512 KB
    float*  part_l = part_m + (size_t)NCHUNK * PP;                    // 512 KB

    nce_zero<<<1, 64, 0, stream>>>(out);
    nce_prep<<<PP / 4, 256, 0, stream>>>(f1, f2, map, qb2, kb2, qsq, ksq, diag2);
    nce_main<<<dim3(PP / 128, NCHUNK), 256, 0, stream>>>(qb2, kb2, qsq, ksq, part_m, part_l);
    nce_final<<<PP / 128, 128, 0, stream>>>(part_m, part_l, diag2, out);
}

// Round 3
// 118.765 us; speedup vs baseline: 2.6400x; 1.1413x over previous
//
#include <hip/hip_runtime.h>
#include <hip/hip_bf16.h>

// Problem: features_1 [1,20000,256] f32, features_2 [1,8192,256] f32, map21 [8192] int
#define PP      8192
#define DIM     256
#define DIMP    272              // 256 + 16 pad dims (norm embedding in 4 of them)
#define NKF     17               // K fragments of 16
#define GS      (32 * DIMP)      // 8704 bf16 elems per 32-row group
#define NCHUNK  16               // column chunks (grid.y); chunk = 512 cols
#define TCOLS   16               // 32-col tiles per chunk
#define ROWBLK  256              // rows per main block (4 waves x 64)
#define NROWBLK (PP / ROWBLK)    // 32
#define TILEB   (32 * DIMP * 2)  // 17408 B per 32-col B tile

typedef __bf16 bf16_t;
using bf16x8 = __attribute__((ext_vector_type(8))) __bf16;
using bf16x4 = __attribute__((ext_vector_type(4))) __bf16;
using f32x4  = __attribute__((ext_vector_type(4))) float;
using f32x16 = __attribute__((ext_vector_type(16))) float;

typedef __attribute__((address_space(1))) void as1_void;
typedef __attribute__((address_space(3))) void as3_void;

#define C2    20.609929155556618          // 1/(T*ln2): -dist -> log2-domain logit
#define MEXP  (-340.0f)                   // fixed log2 shift (safe: see analysis)
#define COEF  ((float)(-(C2 * 1.4142135623730951) * 8388608.0))  // -C2*sqrt(2)*2^23
#define KBIAS ((float)((127.0 + 340.0) * 8388608.0))             // (127 - MEXP)*2^23
#define LN2   0.6931471805599453f

// ---------------------------------------------------------------------------
// Kernel 1: gather + bf16 convert into frag-major layout + norm-embedding pad
// dims + exact fp32 diagonal logit. Also zero-inits part_l / counters / out.
// One wave per row p; lane covers k = lane*4 .. +3.
// Frag-major: elem (p,k) -> G=p>>5, l31=p&31, kk=k>>4, h=(k>>3)&1, j=k&7 at
//   bf16 index G*GS + (kk*64 + h*32 + l31)*8 + j
// ---------------------------------------------------------------------------
__global__ __launch_bounds__(256) void nce_prep(
    const float* __restrict__ f1, const float* __restrict__ f2,
    const int* __restrict__ map,
    bf16_t* __restrict__ qb2, bf16_t* __restrict__ kb2,
    float* __restrict__ diag2, float* __restrict__ part_l,
    unsigned* __restrict__ cnt, float* __restrict__ out)
{
    const int tid  = threadIdx.x;
    const int wave = tid >> 6, lane = tid & 63;
    const int p    = blockIdx.x * 4 + wave;
    const int gtid = blockIdx.x * 256 + tid;

    if (gtid < PP) part_l[gtid] = 0.0f;
    if (gtid < NROWBLK) cnt[gtid] = 0u;
    if (gtid == 0) out[0] = 0.0f;

    const int idx = map[p];
    const f32x4 qv = *(const f32x4*)(f1 + (size_t)idx * DIM + lane * 4);
    const f32x4 kv = *(const f32x4*)(f2 + (size_t)p * DIM + lane * 4);

    float qs = qv[0]*qv[0] + qv[1]*qv[1] + qv[2]*qv[2] + qv[3]*qv[3];
    float ks = kv[0]*kv[0] + kv[1]*kv[1] + kv[2]*kv[2] + kv[3]*kv[3];
    const f32x4 dv = qv - kv;
    float ds = dv[0]*dv[0] + dv[1]*dv[1] + dv[2]*dv[2] + dv[3]*dv[3];

    bf16x4 qo, ko;
    #pragma unroll
    for (int i = 0; i < 4; ++i) { qo[i] = (bf16_t)qv[i]; ko[i] = (bf16_t)kv[i]; }

    const int G = p >> 5, l31 = p & 31;
    const int kk = lane >> 2, h = (lane >> 1) & 1, j0 = (lane & 1) * 4;
    const size_t base = (size_t)G * GS;
    const size_t off  = base + (size_t)(kk * 64 + h * 32 + l31) * 8 + j0;
    *(bf16x4*)(qb2 + off) = qo;
    *(bf16x4*)(kb2 + off) = ko;

    #pragma unroll
    for (int s = 32; s > 0; s >>= 1) {
        qs += __shfl_xor(qs, s);
        ks += __shfl_xor(ks, s);
        ds += __shfl_xor(ds, s);
    }

    // Pad frag kk=16 (dims 256..271). q' = [qhi,qlo,1,1,0..], k' = [1,1,khi,klo,0..]
    // so extra-dim dot = -(qs+ks)/2 with bf16 hi/lo split (norm error < 0.01).
    if (lane < 4) {
        const int hh = lane & 1;           // h of the pad block this lane writes
        bf16x8 v;
        #pragma unroll
        for (int i = 0; i < 8; ++i) v[i] = (bf16_t)0.0f;
        if (lane == 0) {                   // q', dims 256..263
            const float qh = -0.5f * qs;
            const bf16_t q1 = (bf16_t)qh;
            v[0] = q1; v[1] = (bf16_t)(qh - (float)q1);
            v[2] = (bf16_t)1.0f; v[3] = (bf16_t)1.0f;
        } else if (lane == 2) {            // k', dims 256..263
            const float kh = -0.5f * ks;
            const bf16_t k1 = (bf16_t)kh;
            v[0] = (bf16_t)1.0f; v[1] = (bf16_t)1.0f;
            v[2] = k1; v[3] = (bf16_t)(kh - (float)k1);
        }
        bf16_t* dstp = (lane < 2) ? qb2 : kb2;
        *(bf16x8*)(dstp + base + (size_t)(1024 + hh * 32 + l31) * 8) = v;
    }
    if (lane == 0)
        diag2[p] = (float)(-C2) * __builtin_amdgcn_sqrtf(ds);  // exact diag, log2
}

// ---------------------------------------------------------------------------
// Stage one 32-col B tile (17408 B, frag-major) into LDS via global_load_lds
// width-16. LDS dst = wave-uniform base (+ implicit lane*16).
// ---------------------------------------------------------------------------
__device__ __forceinline__ void stage(const bf16_t* __restrict__ kb2,
                                      int Gc, int wave, int lane, char* dst)
{
    const bf16_t* src = kb2 + (size_t)Gc * GS + wave * 512 + lane * 8;
    char* d = dst + wave * 1024;
    #pragma unroll
    for (int j = 0; j < 4; ++j)
        __builtin_amdgcn_global_load_lds((const as1_void*)(src + j * 2048),
                                         (as3_void*)(d + j * 4096), 16, 0, 0);
    if (wave == 0)   // last 1 KB (17th fragment block)
        __builtin_amdgcn_global_load_lds((const as1_void*)(src + 4 * 2048),
                                         (as3_void*)(d + 4 * 4096), 16, 0, 0);
}

// ---------------------------------------------------------------------------
// Kernel 2: fused (QK' GEMM -> -dist^2/2) + fixed-shift exp2 accumulation +
// cross-block merge via atomicAdd + last-block final loss reduction.
// Wave = 64 rows (2 groups) x 32 cols; block = 4 waves = 256 rows.
// Each ds_read_b128 B-frag feeds TWO MFMAs (halves LDS traffic).
// ---------------------------------------------------------------------------
__global__ __launch_bounds__(256, 2) void nce_main(
    const bf16_t* __restrict__ qb2, const bf16_t* __restrict__ kb2,
    const float* __restrict__ diag2, float* __restrict__ part_l,
    unsigned* __restrict__ cnt, float* __restrict__ out)
{
    const int tid  = threadIdx.x, wave = tid >> 6, lane = tid & 63;
    const int l31  = lane & 31, h = lane >> 5;
    const int rb   = blockIdx.x;               // row-block 0..31 (256 rows)
    const int G0   = rb * 8 + wave * 2;        // this wave's first 32-row group
    const int c0g  = blockIdx.y * TCOLS;       // first col-group of chunk

    __shared__ __align__(16) char smem[2][TILEB];
    __shared__ int s_last;

    // A fragments for 2 row groups: 2 x 17 x 4 = 136 VGPRs, 1KB/instr coalesced
    bf16x8 a0[NKF], a1[NKF];
    {
        const bf16_t* ap0 = qb2 + (size_t)G0 * GS + lane * 8;
        const bf16_t* ap1 = ap0 + GS;
        #pragma unroll
        for (int kk = 0; kk < NKF; ++kk) {
            a0[kk] = *(const bf16x8*)(ap0 + kk * 512);
            a1[kk] = *(const bf16x8*)(ap1 + kk * 512);
        }
    }

    float l0[16], l1[16];
    #pragma unroll
    for (int i = 0; i < 16; ++i) { l0[i] = 0.0f; l1[i] = 0.0f; }

    stage(kb2, c0g, wave, lane, smem[0]);

    for (int t = 0; t < TCOLS; ++t) {
        __syncthreads();   // stage(t) landed; buf[(t+1)&1] free
        if (t + 1 < TCOLS) stage(kb2, c0g + t + 1, wave, lane, smem[(t + 1) & 1]);

        const bf16_t* bp = (const bf16_t*)smem[t & 1] + lane * 8;
        f32x16 acc0 = {0,0,0,0,0,0,0,0,0,0,0,0,0,0,0,0};
        f32x16 acc1 = {0,0,0,0,0,0,0,0,0,0,0,0,0,0,0,0};
        #pragma unroll
        for (int kk = 0; kk < NKF; ++kk) {
            const bf16x8 b = *(const bf16x8*)(bp + kk * 512);
            acc0 = __builtin_amdgcn_mfma_f32_32x32x16_bf16(a0[kk], b, acc0, 0, 0, 0);
            acc1 = __builtin_amdgcn_mfma_f32_32x32x16_bf16(a1[kk], b, acc1, 0, 0, 0);
        }
        // acc = -dist^2/2.  2^(lg - MEXP) via bitcast trick:
        //   u = (u32)(t*COEF + KBIAS), t = sqrt(dist^2/2); negative -> clamp 0.
        #pragma unroll
        for (int i = 0; i < 16; ++i) {
            const float t0 = __builtin_amdgcn_sqrtf(-acc0[i]);
            const float u0 = fmaxf(fmaf(t0, COEF, KBIAS), 0.0f);
            l0[i] += __uint_as_float((unsigned)u0);
            const float t1 = __builtin_amdgcn_sqrtf(-acc1[i]);
            const float u1 = fmaxf(fmaf(t1, COEF, KBIAS), 0.0f);
            l1[i] += __uint_as_float((unsigned)u1);
        }
    }

    // sum l across the 32 column-lanes (plain adds — fixed shift, no max merge)
    #pragma unroll
    for (int s = 1; s < 32; s <<= 1) {
        #pragma unroll
        for (int i = 0; i < 16; ++i) {
            l0[i] += __shfl_xor(l0[i], s);
            l1[i] += __shfl_xor(l1[i], s);
        }
    }

    if (l31 == 0) {
        #pragma unroll
        for (int i = 0; i < 16; ++i) {
            const int r = (i & 3) + 8 * (i >> 2) + 4 * h;
            atomicAdd(&part_l[G0 * 32 + r], l0[i]);
            atomicAdd(&part_l[(G0 + 1) * 32 + r], l1[i]);
        }
    }

    __syncthreads();
    if (tid == 0) {
        __threadfence();
        s_last = (atomicAdd(&cnt[rb], 1u) == NCHUNK - 1) ? 1 : 0;
    }
    __syncthreads();
    if (s_last) {
        // all 16 chunk-blocks of this row-block done: finalize 256 rows
        const int row = rb * ROWBLK + tid;
        const float lf = atomicAdd(&part_l[row], 0.0f);   // coherent read
        float v = MEXP + __builtin_amdgcn_logf(lf) - diag2[row];  // log2 domain
        #pragma unroll
        for (int s = 1; s < 64; s <<= 1) v += __shfl_xor(v, s);
        __shared__ float red[4];
        if (lane == 0) red[wave] = v;
        __syncthreads();
        if (tid == 0)
            atomicAdd(out, (red[0] + red[1] + red[2] + red[3]) * (LN2 / (float)PP));
    }
}

// ---------------------------------------------------------------------------
extern "C" void kernel_launch(void* const* d_in, const int* in_sizes, int n_in,
                              void* d_out, int out_size, void* d_ws, size_t ws_size,
                              hipStream_t stream)
{
    const float* f1  = (const float*)d_in[0];   // [20000,256] f32
    const float* f2  = (const float*)d_in[1];   // [8192,256] f32
    const int*   map = (const int*)d_in[2];     // [8192] int
    float* out = (float*)d_out;

    // workspace layout (~8.98 MB)
    char* ws = (char*)d_ws;
    bf16_t*   qb2    = (bf16_t*)ws;                           // 256*8704*2 B
    bf16_t*   kb2    = qb2 + (size_t)256 * GS;                // 256*8704*2 B
    float*    diag2  = (float*)(ws + 2ull * 256 * GS * sizeof(bf16_t));
    float*    part_l = diag2 + PP;
    unsigned* cnt    = (unsigned*)(part_l + PP);

    nce_prep<<<PP / 4, 256, 0, stream>>>(f1, f2, map, qb2, kb2, diag2,
                                         part_l, cnt, out);
    nce_main<<<dim3(NROWBLK, NCHUNK), 256, 0, stream>>>(qb2, kb2, diag2,
                                                        part_l, cnt, out);
}